// Round 2
// baseline (699.515 us; speedup 1.0000x reference)
//
#include <hip/hip_runtime.h>

#define TLEN  4096
#define NROWS 4096
#define K     32            // timesteps per chunk
#define NC    (TLEN / K)    // 128 chunks
#define RPB   64            // rows per block (one per scan lane)
#define NPROD 192           // producer threads (waves 1-3)

__device__ __forceinline__ float fexp2(float x) { return __builtin_amdgcn_exp2f(x); }
__device__ __forceinline__ float frcp(float x)  { return __builtin_amdgcn_rcpf(x); }
// sigmoid given pre-folded arg z = c1*pre + c0 (c1 = -std*log2(e), c0 = std*mean*log2(e))
__device__ __forceinline__ float sigz(float z)  { return frcp(1.0f + fexp2(z)); }

struct Consts {
    // sigmoid-arg folds
    float c1ax, c0ax, c1by, c0by;       // input dirs (producers)
    float c1xx, c0xx, c1yy, c0yy;       // self dirs (scan chain)
    float c1xy, c0xy, c1yx, c0yx;       // cross dirs (general path only)
    // per-source terms: contribution = sigma * (P + Gn*state),  Gn = -g/cap, P = (g/cap)*pot
    float GnA, PA, GnB, PB;             // input->x, input->y
    float Gnxx, Pxx, Gnyx, Pyx;         // x-target state sources (xx, yx)
    float Gnyy, Pyy, Gnxy, Pxy;         // y-target state sources (yy, xy)
};

template<bool SHARED>
__device__ __forceinline__ void run_block(const float4* __restrict__ in4,
                                          float4* __restrict__ out4,
                                          const Consts& k,
                                          float2 (*sig)[K][RPB],
                                          float2 (*outb)[K][RPB]) {
    const int tid = threadIdx.x;
    const int R0  = blockIdx.x * RPB;

    // ---- producer lambdas (waves 1-3) ----
    const int pid = tid - 64;
    auto produce = [&](int c, int buf) {
        // 64 rows x 16 float4 (=32 steps) per chunk; lanes tp-minor for coalescing
        for (int u = pid; u < RPB * (K / 2); u += NPROD) {
            int r  = u >> 4;          // K/2 == 16
            int tp = u & 15;
            float4 f = in4[(size_t)(R0 + r) * (TLEN / 2) + (size_t)c * (K / 2) + tp];
            float sA0 = sigz(__builtin_fmaf(k.c1ax, f.x, k.c0ax));
            float sB0 = sigz(__builtin_fmaf(k.c1by, f.y, k.c0by));
            float sA1 = sigz(__builtin_fmaf(k.c1ax, f.z, k.c0ax));
            float sB1 = sigz(__builtin_fmaf(k.c1by, f.w, k.c0by));
            sig[buf][2 * tp][r]     = make_float2(sA0, sB0);
            sig[buf][2 * tp + 1][r] = make_float2(sA1, sB1);
        }
    };
    auto flush = [&](int c, int buf) {
        for (int u = pid; u < RPB * (K / 2); u += NPROD) {
            int r  = u >> 4;
            int tp = u & 15;
            float2 o0 = outb[buf][2 * tp][r];
            float2 o1 = outb[buf][2 * tp + 1][r];
            out4[(size_t)(R0 + r) * (TLEN / 2) + (size_t)c * (K / 2) + tp] =
                make_float4(o0.x, o0.y, o1.x, o1.y);
        }
    };

    // ---- scan state (wave 0; lane = local row) ----
    float x = 0.0f, y = 1.0f;
    const int lane = tid;

    if (tid >= 64) produce(0, 0);   // prologue: fill sig buffer 0

    for (int c = 0; c < NC; ++c) {
        __syncthreads();
        if (tid < 64) {
            const float2* sgp = &sig[c & 1][0][lane];
            float2*       obp = &outb[c & 1][0][lane];
#pragma unroll
            for (int t = 0; t < K; ++t) {
                float2 sg = sgp[t * RPB];                 // (sigma_a, sigma_b) — imm offset
                // serial chain: fma -> exp2 -> add -> mul -> rcp -> fma
                float zx = __builtin_fmaf(k.c1xx, x, k.c0xx);
                float zy = __builtin_fmaf(k.c1yy, y, k.c0yy);
                float ex = fexp2(zx), ey = fexp2(zy);
                float px = 1.0f + ex, py = 1.0f + ey;
                // state-term numerators (parallel with exp2/rcp latency)
                float t1x = __builtin_fmaf(k.Gnxx, x, k.Pxx);
                float t2x = __builtin_fmaf(k.Gnyx, x, k.Pyx);
                float t1y = __builtin_fmaf(k.Gnyy, y, k.Pyy);
                float t2y = __builtin_fmaf(k.Gnxy, y, k.Pxy);
                float bx = __builtin_fmaf(sg.x, __builtin_fmaf(k.GnA, x, k.PA), x);
                float by = __builtin_fmaf(sg.y, __builtin_fmaf(k.GnB, y, k.PB), y);
                if (SHARED) {
                    // sigma_xx = sigma_xy = py*r; sigma_yy = sigma_yx = px*r; r = 1/(px*py)
                    float r  = frcp(px * py);
                    float Nx = __builtin_fmaf(py, t1x, px * t2x);
                    float Ny = __builtin_fmaf(px, t1y, py * t2y);
                    x = __builtin_fmaf(r, Nx, bx);
                    y = __builtin_fmaf(r, Ny, by);
                } else {
                    float zxy = __builtin_fmaf(k.c1xy, x, k.c0xy);
                    float zyx = __builtin_fmaf(k.c1yx, y, k.c0yx);
                    float exy = fexp2(zxy), eyx = fexp2(zyx);
                    float pxy = 1.0f + exy, pyx = 1.0f + eyx;
                    float rx = frcp(px * pyx);    // x-target: sigma_xx=pyx*rx, sigma_yx=px*rx
                    float ry = frcp(pxy * py);    // y-target: sigma_yy=pxy*ry, sigma_xy=py*ry
                    float Nx = __builtin_fmaf(pyx, t1x, px * t2x);
                    float Ny = __builtin_fmaf(pxy, t1y, py * t2y);
                    x = __builtin_fmaf(rx, Nx, bx);
                    y = __builtin_fmaf(ry, Ny, by);
                }
                obp[t * RPB] = make_float2(x, y);
            }
        } else {
            if (c + 1 < NC) produce(c + 1, (c + 1) & 1);
            if (c >= 1)     flush(c - 1, (c - 1) & 1);
        }
    }
    __syncthreads();
    if (tid >= 64) flush(NC - 1, (NC - 1) & 1);
}

__global__ __launch_bounds__(256, 1)
void memcell(const float* __restrict__ inp, const float* __restrict__ prm,
             float* __restrict__ out) {
    __shared__ float2 sig[2][K][RPB];    // input sigmoids, double-buffered (32 KB)
    __shared__ float2 outb[2][K][RPB];   // output staging, double-buffered  (32 KB)

    const float L2E = 1.4426950408889634f;
    Consts k;
    {
        float capx = prm[0], capy = prm[1];
        float iCx = 1.0f / capx, iCy = 1.0f / capy;
        // dir bases: ax=2 by=6 xy=10 yx=14 xx=18 yy=22 ; fields g,mean,std,pot
        float sd, mn, g;
        sd = prm[4];  mn = prm[3];  k.c1ax = -sd * L2E; k.c0ax = sd * mn * L2E;
        sd = prm[8];  mn = prm[7];  k.c1by = -sd * L2E; k.c0by = sd * mn * L2E;
        sd = prm[20]; mn = prm[19]; k.c1xx = -sd * L2E; k.c0xx = sd * mn * L2E;
        sd = prm[24]; mn = prm[23]; k.c1yy = -sd * L2E; k.c0yy = sd * mn * L2E;
        sd = prm[12]; mn = prm[11]; k.c1xy = -sd * L2E; k.c0xy = sd * mn * L2E;
        sd = prm[16]; mn = prm[15]; k.c1yx = -sd * L2E; k.c0yx = sd * mn * L2E;
        g = prm[2]  * iCx; k.GnA  = -g; k.PA  = g * prm[5];    // ax -> x
        g = prm[6]  * iCy; k.GnB  = -g; k.PB  = g * prm[9];    // by -> y
        g = prm[10] * iCy; k.Gnxy = -g; k.Pxy = g * prm[13];   // xy -> y
        g = prm[14] * iCx; k.Gnyx = -g; k.Pyx = g * prm[17];   // yx -> x
        g = prm[18] * iCx; k.Gnxx = -g; k.Pxx = g * prm[21];   // xx -> x
        g = prm[22] * iCy; k.Gnyy = -g; k.Pyy = g * prm[25];   // yy -> y
    }
    // shared-sigmoid fast path: (mean,std) of xx==xy and yy==yx (block-uniform branch)
    const bool shared = (prm[11] == prm[19]) && (prm[12] == prm[20]) &&
                        (prm[15] == prm[23]) && (prm[16] == prm[24]);

    const float4* in4  = (const float4*)inp;
    float4*       out4 = (float4*)out;
    if (shared) run_block<true >(in4, out4, k, sig, outb);
    else        run_block<false>(in4, out4, k, sig, outb);
}

extern "C" void kernel_launch(void* const* d_in, const int* in_sizes, int n_in,
                              void* d_out, int out_size, void* d_ws, size_t ws_size,
                              hipStream_t stream) {
    (void)in_sizes; (void)n_in; (void)d_ws; (void)ws_size; (void)out_size;
    const float* inp = (const float*)d_in[0];
    const float* prm = (const float*)d_in[1];
    float* out = (float*)d_out;
    // 64 blocks x 256 threads: wave 0 scans 64 rows (1/lane), waves 1-3 stage I/O.
    memcell<<<dim3(NROWS / RPB), dim3(256), 0, stream>>>(inp, prm, out);
}

// Round 3
// 456.938 us; speedup vs baseline: 1.5309x; 1.5309x over previous
//
#include <hip/hip_runtime.h>
#include <hip/hip_fp16.h>

#define TLEN  4096
#define NROWS 4096
#define PLANE ((size_t)TLEN * NROWS)   // halves per sigmoid plane
#define UN    8                        // exact-path unroll (float4s per iter)

__device__ __forceinline__ float fexp2(float x) { return __builtin_amdgcn_exp2f(x); }
__device__ __forceinline__ float frcp(float x)  { return __builtin_amdgcn_rcpf(x); }
__device__ __forceinline__ float sigz(float z)  { return frcp(1.0f + fexp2(z)); }

// Swap adjacent lanes (lane ^ 1) via DPP quad_perm [1,0,3,2] = 0xB1.
__device__ __forceinline__ float lane_swap1(float v) {
    int r = __builtin_amdgcn_update_dpp(0, __float_as_int(v), 0xB1, 0xF, 0xF, true);
    return __int_as_float(r);
}

// ---------------------------------------------------------------------------
// Pass 1: input sigmoids, exact, massively parallel, fp16 planar output.
// ws layout: plane A = sigma(ax dir) [row][t], plane B = sigma(by dir).
// ---------------------------------------------------------------------------
__global__ __launch_bounds__(256, 1)
void sig_pass(const float4* __restrict__ in4, const float* __restrict__ prm,
              __half* __restrict__ wsb) {
    const int gid = blockIdx.x * 256 + threadIdx.x;
    const int row = gid >> 11;          // 2048 float4 per row
    const int tp  = gid & 2047;
    const float L2E = 1.4426950408889634f;
    const float c1a = -prm[4] * L2E, c0a = prm[4] * prm[3] * L2E;
    const float c1b = -prm[8] * L2E, c0b = prm[8] * prm[7] * L2E;
    float4 f = in4[(size_t)row * 2048 + tp];
    float sA0 = sigz(__builtin_fmaf(c1a, f.x, c0a));
    float sB0 = sigz(__builtin_fmaf(c1b, f.y, c0b));
    float sA1 = sigz(__builtin_fmaf(c1a, f.z, c0a));
    float sB1 = sigz(__builtin_fmaf(c1b, f.w, c0b));
    __half2* pa = (__half2*)(wsb + (size_t)row * TLEN);
    __half2* pb = (__half2*)(wsb + PLANE + (size_t)row * TLEN);
    pa[tp] = __floats2half2_rn(sA0, sA1);
    pb[tp] = __floats2half2_rn(sB0, sB1);
}

// ---------------------------------------------------------------------------
// Exact scan (round-1 proven path) — fallback for general params.
// ---------------------------------------------------------------------------
struct LaneConst {
    float c1_in, c0_in, c1_sf, c0_sf, c1_ot, c0_ot;
    float gS_in, gS_cr, gS_sf, gP_in, gP_cr, gP_sf;
};

template<bool SHARED>
__device__ __forceinline__ float do_step_exact(float s, float pre_in, const LaneConst& k) {
    float e_in = fexp2(__builtin_fmaf(k.c1_in, pre_in, k.c0_in));
    float e_sf = fexp2(__builtin_fmaf(k.c1_sf, s, k.c0_sf));
    float sig_in = frcp(1.0f + e_in);
    float sig_sf = frcp(1.0f + e_sf);
    float sig_ot;
    if (SHARED) sig_ot = sig_sf;
    else        sig_ot = frcp(1.0f + fexp2(__builtin_fmaf(k.c1_ot, s, k.c0_ot)));
    float sig_cr = lane_swap1(sig_ot);
    float S = __builtin_fmaf(k.gS_in, sig_in, __builtin_fmaf(k.gS_cr, sig_cr, k.gS_sf * sig_sf));
    float P = __builtin_fmaf(k.gP_in, sig_in, __builtin_fmaf(k.gP_cr, sig_cr, k.gP_sf * sig_sf));
    return s + __builtin_fmaf(S, -s, P);
}

template<bool SHARED>
__device__ void run_exact(const float* __restrict__ inp, const float* __restrict__ prm,
                          float* __restrict__ out) {
    const int tid = blockIdx.x * 64 + threadIdx.x;
    const int row = tid >> 1;
    const int par = tid & 1;
    const float L2E = 1.4426950408889634f;
    const int inB = par ? 6 : 2, sfB = par ? 22 : 18, otB = par ? 14 : 10, crB = par ? 10 : 14;
    const float invc = 1.0f / prm[par];
    LaneConst k;
    float sd = prm[inB + 2], mn = prm[inB + 1];
    k.c1_in = -sd * L2E; k.c0_in = sd * mn * L2E;
    sd = prm[sfB + 2]; mn = prm[sfB + 1];
    k.c1_sf = -sd * L2E; k.c0_sf = sd * mn * L2E;
    sd = prm[otB + 2]; mn = prm[otB + 1];
    k.c1_ot = -sd * L2E; k.c0_ot = sd * mn * L2E;
    k.gS_in = prm[inB] * invc; k.gP_in = k.gS_in * prm[inB + 3];
    k.gS_sf = prm[sfB] * invc; k.gP_sf = k.gS_sf * prm[sfB + 3];
    k.gS_cr = prm[crB] * invc; k.gP_cr = k.gS_cr * prm[crB + 3];

    const float4* __restrict__ src = (const float4*)inp + (size_t)row * (TLEN / 2);
    float* __restrict__ dst = out + (size_t)row * (TLEN * 2) + par;
    float s = par ? 1.0f : 0.0f;

    float4 cur[UN], nxt[UN];
#pragma unroll
    for (int j = 0; j < UN; ++j) cur[j] = src[j];
    const int NIT = TLEN / (2 * UN);
    for (int it = 0; it < NIT; ++it) {
        if (it + 1 < NIT) {
#pragma unroll
            for (int j = 0; j < UN; ++j) nxt[j] = src[(it + 1) * UN + j];
        }
        float* dptr = dst + it * (UN * 4);
#pragma unroll
        for (int j = 0; j < UN; ++j) {
            float4 f = cur[j];
            s = do_step_exact<SHARED>(s, par ? f.y : f.x, k);
            dptr[j * 4] = s;
            s = do_step_exact<SHARED>(s, par ? f.w : f.z, k);
            dptr[j * 4 + 2] = s;
        }
#pragma unroll
        for (int j = 0; j < UN; ++j) cur[j] = nxt[j];
    }
}

// ---------------------------------------------------------------------------
// Fast scan: incremental exponential tracking. No transcendental on the
// loop-carried chain — pure fma/mul/DPP (~11 deps/step).
//   x-lane (par=0) tracks e = 2^(-std_xx*L2E*(x-mean_xx)), p = 1+e,
//   r ~ 1/(px*py) refined by one Newton step per iteration.
//   dx = sg_a*(GnA*x+PA) + r*( po*(Gn1*x+P1) + p*(Gn2*x+P2) )
// ---------------------------------------------------------------------------
__device__ void run_fast(const float* __restrict__ prm, const __half* __restrict__ wsb,
                         float* __restrict__ out) {
    const int tid = blockIdx.x * 64 + threadIdx.x;
    const int row = tid >> 1;
    const int par = tid & 1;
    const float L2E = 1.4426950408889634f;
    const int inB = par ? 6 : 2, sfB = par ? 22 : 18, t2B = par ? 10 : 14;
    const float ic = 1.0f / prm[par];
    const float g1 = prm[sfB] * ic,  P1 = g1 * prm[sfB + 3], Gn1 = -g1; // self sigma coeff
    const float g2 = prm[t2B] * ic,  P2 = g2 * prm[t2B + 3], Gn2 = -g2; // cross sigma coeff
    const float gA = prm[inB] * ic,  PA = gA * prm[inB + 3], GnA = -gA; // input coeff
    const float c1 = -prm[sfB + 2] * L2E;            // w = c1*dx
    const float mean_s = prm[sfB + 1];
    // 2^w - 1 Taylor deg-3 (|w| <= 0.05 guaranteed by guard): exact coefficients
    const float T1 = 0.6931471805599453f;            // ln2
    const float T2 = 0.2402265069591007f;            // ln2^2/2
    const float T3 = 0.05550410866482158f;           // ln2^3/6

    float x = par ? 1.0f : 0.0f;
    float e = fexp2(c1 * (x - mean_s));              // exact init
    float p = 1.0f + e;
    float po0 = lane_swap1(p);
    float d0 = p * po0;
    float r = frcp(d0);
    r = r * __builtin_fmaf(d0, -r, 2.0f);            // 2x NR at init
    r = r * __builtin_fmaf(d0, -r, 2.0f);

    const uint4* __restrict__ sp = (const uint4*)(wsb + (par ? PLANE : 0) + (size_t)row * TLEN);
    float* __restrict__ dst = out + (size_t)row * (TLEN * 2) + par;

    uint4 cv0 = sp[0], cv1 = sp[1], nv0, nv1;
    const int NCH = TLEN / 16;
    for (int c = 0; c < NCH; ++c) {
        if (c + 1 < NCH) { nv0 = sp[(c + 1) * 2]; nv1 = sp[(c + 1) * 2 + 1]; }
        const __half* h0 = (const __half*)&cv0;
        const __half* h1 = (const __half*)&cv1;
        float* dp = dst + c * 32;
#pragma unroll
        for (int t = 0; t < 16; ++t) {
            float sg = __half2float(t < 8 ? h0[t] : h1[t - 8]);
            // off-chain terms (depend on x only)
            float t1v = __builtin_fmaf(Gn1, x, P1);
            float t2v = __builtin_fmaf(Gn2, x, P2);
            float Av  = __builtin_fmaf(GnA, x, PA);
            float bxm = sg * Av;
            // chain: DPP -> d -> NR -> dx -> w -> taylor -> e,p update
            float po = lane_swap1(p);
            float d  = p * po;
            float nr = __builtin_fmaf(d, -r, 2.0f);
            r = r * nr;                               // r ~= 1/d (one NR, self-correcting)
            float m  = p * t2v;
            float Nx = __builtin_fmaf(po, t1v, m);
            float dx = __builtin_fmaf(r, Nx, bxm);
            x = x + dx;
            dp[2 * t] = x;
            float w = c1 * dx;
            float h = __builtin_fmaf(__builtin_fmaf(T3, w, T2), w, T1);
            float u = w * h;                          // u = 2^w - 1
            float pn = __builtin_fmaf(e, u, p);       // p' = 1 + e*(1+u)
            e = __builtin_fmaf(e, u, e);              // e' = e*(1+u)
            p = pn;
        }
        cv0 = nv0; cv1 = nv1;
    }
}

__global__ __launch_bounds__(64, 1)
void scan_pass(const float* __restrict__ inp, const float* __restrict__ prm,
               const __half* __restrict__ wsb, float* __restrict__ out) {
    // Device-uniform guard: fast path requires
    //  - shared (mean,std) between self & cross state dirs (xx==xy, yy==yx)
    //  - all g >= 0, caps > 0  -> states stay in hull{x0, pots}
    //  - sum(g/cap) <= 0.25    -> no overshoot, |dx| <= s*W
    //  - |w| = |c1*dx| <= 0.05 -> deg-3 Taylor valid
    //  - |z| <= 20             -> e = 2^z no overflow
    const bool shared = (prm[11] == prm[19]) && (prm[12] == prm[20]) &&
                        (prm[15] == prm[23]) && (prm[16] == prm[24]);
    const float capx = prm[0], capy = prm[1];
    const bool gpos = prm[2] >= 0.f && prm[6] >= 0.f && prm[10] >= 0.f &&
                      prm[14] >= 0.f && prm[18] >= 0.f && prm[22] >= 0.f &&
                      capx > 0.f && capy > 0.f;
    const float sx = (prm[2] + prm[14] + prm[18]) / capx;
    const float sy = (prm[6] + prm[10] + prm[22]) / capy;
    const float lox = fminf(0.f, fminf(prm[5], fminf(prm[17], prm[21])));
    const float hix = fmaxf(0.f, fmaxf(prm[5], fmaxf(prm[17], prm[21])));
    const float loy = fminf(1.f, fminf(prm[9], fminf(prm[13], prm[25])));
    const float hiy = fmaxf(1.f, fmaxf(prm[9], fmaxf(prm[13], prm[25])));
    const float L2E = 1.4426950408889634f;
    const float cx = prm[20] * L2E, cy = prm[24] * L2E;
    const float wbx = cx * sx * (hix - lox), wby = cy * sy * (hiy - loy);
    const float zmx = cx * fmaxf(fabsf(lox - prm[19]), fabsf(hix - prm[19]));
    const float zmy = cy * fmaxf(fabsf(loy - prm[23]), fabsf(hiy - prm[23]));
    const bool fast = shared && gpos && sx <= 0.25f && sy <= 0.25f &&
                      wbx <= 0.05f && wby <= 0.05f && zmx <= 20.f && zmy <= 20.f;
    if (fast) {
        run_fast(prm, wsb, out);
    } else {
        if (shared) run_exact<true >(inp, prm, out);
        else        run_exact<false>(inp, prm, out);
    }
}

// Standalone exact kernel (used when ws is too small for the sigmoid planes).
__global__ __launch_bounds__(64, 1)
void memcell_exact(const float* __restrict__ inp, const float* __restrict__ prm,
                   float* __restrict__ out) {
    const bool shared = (prm[11] == prm[19]) && (prm[12] == prm[20]) &&
                        (prm[15] == prm[23]) && (prm[16] == prm[24]);
    if (shared) run_exact<true >(inp, prm, out);
    else        run_exact<false>(inp, prm, out);
}

extern "C" void kernel_launch(void* const* d_in, const int* in_sizes, int n_in,
                              void* d_out, int out_size, void* d_ws, size_t ws_size,
                              hipStream_t stream) {
    (void)in_sizes; (void)n_in; (void)out_size;
    const float* inp = (const float*)d_in[0];
    const float* prm = (const float*)d_in[1];
    float* out = (float*)d_out;
    const size_t need = 2 * PLANE * sizeof(__half);   // 67.1 MB
    if (ws_size >= need) {
        __half* wsb = (__half*)d_ws;
        sig_pass<<<dim3((NROWS * (TLEN / 2)) / 256), dim3(256), 0, stream>>>(
            (const float4*)inp, prm, wsb);
        scan_pass<<<dim3((NROWS * 2) / 64), dim3(64), 0, stream>>>(inp, prm, wsb, out);
    } else {
        memcell_exact<<<dim3((NROWS * 2) / 64), dim3(64), 0, stream>>>(inp, prm, out);
    }
}